// Round 7
// baseline (158.580 us; speedup 1.0000x reference)
//
#include <hip/hip_runtime.h>
#include <math.h>

// Problem constants
#define BQ 64
#define NOBJ 5
#define CIN 3
#define IMG_H 64
#define IMG_W 96
#define OH 32
#define OW 48
#define NPAIR 25
#define PP 4
#define CONV_OUT 32

// Tiling: each block = (src, b, rowgroup of 2 output rows); 512 threads = 8 waves.
// LDS holds ONE output row (48 pos) at a time -> 15.4 KB -> 4 blocks/CU
// (round 6: 30.7 KB two-row buffer capped residency at 2 blocks/CU = 50% occ).
#define NRG 16                          // 32 output rows / 2
#define ROWPOS 48                       // 1 output row = 48 cols
#define XK 32                           // padded K (27 real + bias + zeros)
#define X_U32 (NOBJ * ROWPOS * XK / 2)  // 3840 u32 = 15.4 KB (f16 im2col)
#define X_UNITS (NOBJ * ROWPOS * 4)     // 960 8-elem units

#define NPRED (2 * 1600 * PP)           // 12800
#define ADJ_N (BQ * 1600)               // 102400

typedef __fp16   h2 __attribute__((ext_vector_type(2)));     // cvt_pkrtz result type
typedef _Float16 half8 __attribute__((ext_vector_type(8)));  // MFMA A/B operand
typedef float    float4_ __attribute__((ext_vector_type(4)));
typedef float    float2_ __attribute__((ext_vector_type(2)));
typedef unsigned int uint4_ __attribute__((ext_vector_type(4)));

// T[src][b][rg][pair][mt]; mt = 16-oc tile 0..7 (p = mt>>1). Fully written,
// no memset, no atomics. src==1 blocks also write the adj mask.
//
// HISTORY (keep): (512,4) launch bounds act as a 64-VGPR cap here -> 448 MB
// scratch spill (r2/r3). Reduce-MFMA epilogue (4 regs/pair x 25) always
// spills or kills occupancy (r4/r5). LDS XOR swizzle: conflicts 1.97M -> 0
// but only ~2 us (cheap-conflict regime). This round: halve LDS tile to
// double resident blocks (50% occ -> target ~100%).
__global__ __launch_bounds__(512) void conv_pair_mfma(
    const float* __restrict__ state,
    const float* __restrict__ state_next,
    const float* __restrict__ conv_w,
    const float* __restrict__ conv_b,
    const float* __restrict__ w2,
    float* __restrict__ T,
    float* __restrict__ out)
{
    __shared__ __align__(16) unsigned int sX32[X_U32];   // 15.4 KB f16 im2col

    const int tid = threadIdx.x;
    const int rg  = blockIdx.x;     // 0..15
    const int b   = blockIdx.y;     // 0..63
    const int src = blockIdx.z;     // 0..1

    const float* g = (src == 0 ? state : state_next)
                   + (size_t)b * NOBJ * CIN * IMG_H * IMG_W;
    const int R0 = rg * 4;          // first input row of this rowgroup

    // ---- adj mask from src==1 blocks (independent; pre-barrier) ----
    if (src == 1 && tid < 100) {
        int a  = (rg + NRG * b) * 100 + tid;     // 1024 blocks x 100 = 102400
        int bb = a / 1600;
        int t  = a - bb * 1600;
        out[NPRED + a] = (t / NPAIR == bb) ? 1.0f : 0.0f;
    }

    const int wave = tid >> 6;      // 0..7 -> mt
    const int lane = tid & 63;
    const int quad = lane >> 4;
    const int ocl  = lane & 15;

    const int mt  = wave;
    const int p   = mt >> 1;
    const int row = mt * 16 + ocl;  // this lane's conv_w row (oc)

    // ---- per-lane weights as f16 (global loads issue early, overlap staging)
    half8 wa, wb;
    #pragma unroll
    for (int j = 0; j < 8; ++j) {
        int k = quad * 8 + j;
        float va = 0.f, vb = 0.f;
        if (k < 27) {
            va = conv_w[row * 54 + k];
            vb = conv_w[row * 54 + 27 + k];
        } else if (k == 27) {
            va = conv_b[row];       // bias pairs with 1.0 lane in X
        }
        wa[j] = (_Float16)va;
        wb[j] = (_Float16)vb;
    }
    h2 w2h01, w2h23;
    {
        const float* wp = w2 + p * CONV_OUT + (mt & 1) * 16 + quad * 4;
        w2h01 = __builtin_amdgcn_cvt_pkrtz(wp[0], wp[1]);
        w2h23 = __builtin_amdgcn_cvt_pkrtz(wp[2], wp[3]);
    }

    // ---- im2col k-decode tables (thread-invariant, hoisted out of phases)
    const int subk = tid & 3;
    int koff[8], khv[8], kwv[8];
    float padf[8];
    bool kval[8];
    #pragma unroll
    for (int j = 0; j < 8; ++j) {
        int k = subk * 8 + j;
        if (k < 27) {
            int ci = k / 9;
            int r9 = k - ci * 9;
            int kh = r9 / 3;
            int kw = r9 - kh * 3;
            koff[j] = ci * (IMG_H * IMG_W) + kh * IMG_W + kw;
            khv[j] = kh; kwv[j] = kw; kval[j] = true; padf[j] = 0.f;
        } else {
            koff[j] = 0; khv[j] = 0; kwv[j] = 0; kval[j] = false;
            padf[j] = (k == 27) ? 1.0f : 0.f;
        }
    }

    const float4_ zero4 = {0.f, 0.f, 0.f, 0.f};
    const h2 hz = {(__fp16)0.f, (__fp16)0.f};

    float acc[NPAIR];
    #pragma unroll
    for (int q = 0; q < NPAIR; ++q) acc[q] = 0.f;

    // ---- two phases: stage one output row (48 pos), compute its 3 col-tiles.
    #pragma unroll
    for (int rlp = 0; rlp < 2; ++rlp) {
        if (rlp) __syncthreads();       // protect buffer until all reads done

        // stage f16 im2col sX[obj][pos48][k] for input row gr0 = R0 + 2*rlp.
        // 16B chunk index XOR-swizzled with (pos>>1)&3 (verified r2-r6:
        // SQ_LDS_BANK_CONFLICT 1.97M -> 0).
        {
            const int gr0 = R0 + 2 * rlp;
            for (int u = tid; u < X_UNITS; u += 512) {
                int pl  = (u >> 2) % ROWPOS;
                int obj = u / (ROWPOS * 4);
                int gc0 = 2 * pl;
                const float* gp = g + obj * (CIN * IMG_H * IMG_W) + gr0 * IMG_W + gc0;
                float fv[8];
                #pragma unroll
                for (int j = 0; j < 8; ++j) {
                    float v = padf[j];
                    if (kval[j] && (gr0 + khv[j] < IMG_H) && (gc0 + kwv[j] < IMG_W))
                        v = gp[koff[j]];
                    fv[j] = v;
                }
                uint4_ w4;
                w4.x = __builtin_bit_cast(unsigned int, __builtin_amdgcn_cvt_pkrtz(fv[0], fv[1]));
                w4.y = __builtin_bit_cast(unsigned int, __builtin_amdgcn_cvt_pkrtz(fv[2], fv[3]));
                w4.z = __builtin_bit_cast(unsigned int, __builtin_amdgcn_cvt_pkrtz(fv[4], fv[5]));
                w4.w = __builtin_bit_cast(unsigned int, __builtin_amdgcn_cvt_pkrtz(fv[6], fv[7]));
                int swk = subk ^ ((pl >> 1) & 3);
                *(uint4_*)&sX32[(size_t)(obj * (ROWPOS * 16) + pl * 16 + swk * 4)] = w4;
            }
        }

        __syncthreads();

        #pragma unroll
        for (int nt3 = 0; nt3 < 3; ++nt3) {    // 3 col-tiles of 16 in this row
            const int pos = nt3 * 16 + ocl;    // 0..47
            const int sw  = (pos >> 1) & 3;
            const int sbase = pos * 16 + ((quad ^ sw) << 2);

            half8 xf[NOBJ];
            h2 ah01[NOBJ], ah23[NOBJ];
            #pragma unroll
            for (int obj = 0; obj < NOBJ; ++obj) {
                xf[obj] = *(const half8*)&sX32[sbase + obj * (ROWPOS * 16)];
                float4_ a = __builtin_amdgcn_mfma_f32_16x16x32_f16(wa, xf[obj], zero4, 0, 0, 0);
                ah01[obj] = __builtin_amdgcn_cvt_pkrtz(a[0], a[1]);
                ah23[obj] = __builtin_amdgcn_cvt_pkrtz(a[2], a[3]);
            }

            #pragma unroll
            for (int jo = 0; jo < NOBJ; ++jo) {
                float4_ bq = __builtin_amdgcn_mfma_f32_16x16x32_f16(wb, xf[jo], zero4, 0, 0, 0);
                h2 bh01 = __builtin_amdgcn_cvt_pkrtz(bq[0], bq[1]);
                h2 bh23 = __builtin_amdgcn_cvt_pkrtz(bq[2], bq[3]);
                #pragma unroll
                for (int i = 0; i < NOBJ; ++i) {
                    h2 s0 = ah01[i] + bh01;                        // v_pk_add_f16
                    h2 s1 = ah23[i] + bh23;
                    s0 = __builtin_elementwise_max(s0, hz);        // v_pk_max_f16
                    s1 = __builtin_elementwise_max(s1, hz);
                    float t0 = __builtin_amdgcn_fdot2(s0, w2h01, acc[i * NOBJ + jo], false);
                    acc[i * NOBJ + jo] = __builtin_amdgcn_fdot2(s1, w2h23, t0, false);
                }
            }
        }
    }

    // ---- wave-reduce each pair across 64 lanes; direct store (no atomics) ----
    float myv = 0.f;
    #pragma unroll
    for (int q = 0; q < NPAIR; ++q) {
        float rr = acc[q];
        #pragma unroll
        for (int off = 32; off > 0; off >>= 1)
            rr += __shfl_xor(rr, off, 64);
        if (lane == q) myv = rr;
    }
    if (lane < NPAIR)
        T[((((size_t)src * BQ + b) * NRG + rg) * NPAIR + lane) * 8 + mt] = myv;
}

// predicates: 4 threads per output, each sums 4 rowgroups via float2 loads,
// then a 2-level shfl combine. 51200 threads = 200 blocks.
__global__ __launch_bounds__(256) void pred_kernel(
    const float* __restrict__ T,
    const float* __restrict__ b2,
    const float* __restrict__ temp,
    float* __restrict__ out)
{
    int gid = blockIdx.x * blockDim.x + threadIdx.x;
    int idx = gid >> 2;
    int h   = gid & 3;
    if (idx >= NPRED) return;
    int p   = idx & 3;
    int t   = (idx >> 2) % 1600;
    int src = idx / 6400;
    int bb  = t / NPAIR;
    int pr  = t - bb * NPAIR;
    const float* base = T + ((((size_t)src * BQ + bb) * NRG) * NPAIR + pr) * 8 + 2 * p;
    float sum = 0.f;
    #pragma unroll
    for (int r = 0; r < 4; ++r) {
        int rgi = h * 4 + r;
        float2_ v = *(const float2_*)&base[(size_t)rgi * NPAIR * 8];
        sum += v[0] + v[1];
    }
    sum += __shfl_xor(sum, 1, 64);
    sum += __shfl_xor(sum, 2, 64);
    if (h == 0) {
        float logit = sum * (1.0f / (OH * OW)) + b2[p];
        float x = logit / temp[0];
        out[idx] = 1.0f / (1.0f + expf(-x));
    }
}

extern "C" void kernel_launch(void* const* d_in, const int* in_sizes, int n_in,
                              void* d_out, int out_size, void* d_ws, size_t ws_size,
                              hipStream_t stream)
{
    const float* state      = (const float*)d_in[0];
    const float* state_next = (const float*)d_in[1];
    const float* conv_w     = (const float*)d_in[2];
    const float* conv_b     = (const float*)d_in[3];
    const float* w2         = (const float*)d_in[4];
    const float* b2         = (const float*)d_in[5];
    // d_in[6] = n_obj (always 5)
    const float* temp       = (const float*)d_in[7];

    float* out = (float*)d_out;
    float* T   = (float*)d_ws;              // [2][64][16][25][8] floats = 1.64 MB

    dim3 grid1(NRG, BQ, 2);                 // 2048 blocks x 512 threads
    conv_pair_mfma<<<grid1, 512, 0, stream>>>(state, state_next, conv_w, conv_b,
                                              w2, T, out);

    pred_kernel<<<(NPRED * 4 + 255) / 256, 256, 0, stream>>>(T, b2, temp, out);
}